// Round 1
// baseline (1664.870 us; speedup 1.0000x reference)
//
#include <hip/hip_runtime.h>
#include <hip/hip_bf16.h>

// DecoderRNN: emb gather+relu -> gi GEMM (hoisted) -> 64 sequential GRU steps
// (MFMA, gates fused) -> output projection GEMM (4096x32000x1024 bf16 MFMA)
// with permuted (b,s,v) store + bias.
//
// Sizes: VOCAB=32000, EMB=512, HID=1024, SEQ=64, BATCH=64.

#define VOCAB 32000
#define EMB 512
#define HID 1024
#define SEQ 64
#define BATCH 64

typedef __bf16 bf16_8 __attribute__((ext_vector_type(8)));
typedef float f32x4 __attribute__((ext_vector_type(4)));

__device__ __forceinline__ unsigned short f32_to_bf16_rne(float f) {
    unsigned int u = __float_as_uint(f);
    u = (u + 0x7FFFu + ((u >> 16) & 1u)) >> 16;
    return (unsigned short)u;
}

__device__ __forceinline__ void gld_lds16(const unsigned short* g, unsigned short* l) {
    __builtin_amdgcn_global_load_lds(
        (__attribute__((address_space(1))) void*)g,
        (__attribute__((address_space(3))) void*)l, 16, 0, 0);
}

// ---------------- converters ----------------
__global__ void f32_to_bf16_vec(const float* __restrict__ in,
                                unsigned short* __restrict__ out, int n4) {
    int i = blockIdx.x * blockDim.x + threadIdx.x;
    if (i < n4) {
        float4 v = ((const float4*)in)[i];
        ushort4 o;
        o.x = f32_to_bf16_rne(v.x);
        o.y = f32_to_bf16_rne(v.y);
        o.z = f32_to_bf16_rne(v.z);
        o.w = f32_to_bf16_rne(v.w);
        ((ushort4*)out)[i] = o;
    }
}

__global__ void init_h_kernel(const float* __restrict__ h0,
                              float* __restrict__ hf0,
                              unsigned short* __restrict__ hb0) {
    int i = blockIdx.x * blockDim.x + threadIdx.x;  // 65536
    float v = h0[i];
    hf0[i] = v;
    hb0[i] = f32_to_bf16_rne(v);
}

// ---------------- embedding gather + relu -> bf16 ----------------
__global__ void embed_relu_kernel(const int* __restrict__ x,
                                  const float* __restrict__ emb,
                                  unsigned short* __restrict__ e_bf) {
    int idx = blockIdx.x * blockDim.x + threadIdx.x;  // 4096*512
    int row = idx >> 9;       // (s*64+b)
    int k = idx & 511;
    int s = row >> 6, b = row & 63;
    int tok = (s == 0) ? 2 : x[(s - 1) * 64 + b];
    float v = emb[(long)tok * EMB + k];
    v = v > 0.f ? v : 0.f;   // relu (also covers padding row 0, already zero)
    e_bf[idx] = f32_to_bf16_rne(v);
}

// ---------------- bf16 MFMA GEMM: C(M,N) = A(M,K) * B(N,K)^T + bias ----------------
// 128x128 block tile, BK=32, 4 waves (2x2), each wave 64x64 via 4x4 mfma_16x16x32.
// permute=0: C[r*N+c]; permute=1: C[((r&63)*SEQ + (r>>6))*N + c]  (b,s,v) layout.
__global__ __launch_bounds__(256) void gemm_bf16_nt(
    const unsigned short* __restrict__ A,
    const unsigned short* __restrict__ B,
    const float* __restrict__ bias,
    float* __restrict__ C,
    int M, int N, int K, int permute) {
    __shared__ unsigned short As[128 * 32];
    __shared__ unsigned short Bs[128 * 32];

    const int tid = threadIdx.x;
    const int wave = tid >> 6;
    const int lane = tid & 63;
    const int bm = blockIdx.y, bn = blockIdx.x;
    const int wm = (wave >> 1) * 64;
    const int wn = (wave & 1) * 64;

    f32x4 acc[4][4];
#pragma unroll
    for (int i = 0; i < 4; i++)
#pragma unroll
        for (int j = 0; j < 4; j++) acc[i][j] = (f32x4){0.f, 0.f, 0.f, 0.f};

    // staging: thread t loads 8 bf16 (16B); chunk q covers 64 rows
    const int r0 = tid >> 2;              // 0..63
    const int c0 = (tid & 3) << 3;        // 0,8,16,24
    const unsigned short* Ap0 = A + (long)(bm * 128 + r0) * K + c0;
    const unsigned short* Ap1 = A + (long)(bm * 128 + 64 + r0) * K + c0;
    const unsigned short* Bp0 = B + (long)(bn * 128 + r0) * K + c0;
    const unsigned short* Bp1 = B + (long)(bn * 128 + 64 + r0) * K + c0;
    // wave-uniform LDS dest bases (elements): (q*256 + wave*64)*8
    unsigned short* AsW0 = &As[wave * 512];
    unsigned short* AsW1 = &As[2048 + wave * 512];
    unsigned short* BsW0 = &Bs[wave * 512];
    unsigned short* BsW1 = &Bs[2048 + wave * 512];

    const int fr = lane & 15;
    const int fk = (lane >> 4) << 3;

    for (int k0 = 0; k0 < K; k0 += 32) {
        __syncthreads();
        gld_lds16(Ap0 + k0, AsW0);
        gld_lds16(Ap1 + k0, AsW1);
        gld_lds16(Bp0 + k0, BsW0);
        gld_lds16(Bp1 + k0, BsW1);
        __syncthreads();  // drains vmcnt before barrier

        bf16_8 af[4], bf[4];
#pragma unroll
        for (int mt = 0; mt < 4; mt++)
            af[mt] = *(const bf16_8*)&As[(wm + mt * 16 + fr) * 32 + fk];
#pragma unroll
        for (int nt = 0; nt < 4; nt++)
            bf[nt] = *(const bf16_8*)&Bs[(wn + nt * 16 + fr) * 32 + fk];
#pragma unroll
        for (int mt = 0; mt < 4; mt++)
#pragma unroll
            for (int nt = 0; nt < 4; nt++)
                acc[mt][nt] = __builtin_amdgcn_mfma_f32_16x16x32_bf16(
                    af[mt], bf[nt], acc[mt][nt], 0, 0, 0);
    }

    // epilogue: C layout col=lane&15, row=(lane>>4)*4+i
    const int er = lane >> 4;
    const int ec = lane & 15;
#pragma unroll
    for (int nt = 0; nt < 4; nt++) {
        const int gc = bn * 128 + wn + nt * 16 + ec;
        const float bv = bias[gc];
#pragma unroll
        for (int mt = 0; mt < 4; mt++) {
#pragma unroll
            for (int i = 0; i < 4; i++) {
                int gr = bm * 128 + wm + mt * 16 + er * 4 + i;
                long off;
                if (permute) off = (long)((gr & 63) * SEQ + (gr >> 6)) * N + gc;
                else off = (long)gr * N + gc;
                C[off] = acc[mt][nt][i] + bv;
            }
        }
    }
}

// ---------------- GRU step: gh = h @ w_hh^T, fused gates ----------------
// grid 256 blocks x 64 threads. block b: m-tile (b&3) -> batch rows, j-tile (b>>2)*16.
// Each wave computes 3 gate tiles (16x16) over K=1024 and applies gate math.
__global__ __launch_bounds__(64) void gru_step_kernel(
    const unsigned short* __restrict__ hb_s,   // (64,1024) bf16
    const float* __restrict__ hf_s,            // (64,1024) f32
    const unsigned short* __restrict__ w_hh,   // (3072,1024) bf16
    const float* __restrict__ gi_s,            // (64,3072) f32 (includes b_ih)
    const float* __restrict__ b_hh,            // (3072)
    unsigned short* __restrict__ hb_out,
    float* __restrict__ hf_out) {
    const int lane = threadIdx.x;
    const int mt = blockIdx.x & 3;
    const int j0 = (blockIdx.x >> 2) * 16;

    const int fr = lane & 15;
    const int fk = (lane >> 4) << 3;

    f32x4 accr = (f32x4){0.f, 0.f, 0.f, 0.f};
    f32x4 accz = (f32x4){0.f, 0.f, 0.f, 0.f};
    f32x4 accn = (f32x4){0.f, 0.f, 0.f, 0.f};

    const unsigned short* aptr = hb_s + (mt * 16 + fr) * HID + fk;
    const unsigned short* bpr = w_hh + (long)(j0 + fr) * HID + fk;
    const unsigned short* bpz = w_hh + (long)(HID + j0 + fr) * HID + fk;
    const unsigned short* bpn = w_hh + (long)(2 * HID + j0 + fr) * HID + fk;

#pragma unroll 8
    for (int k = 0; k < HID; k += 32) {
        bf16_8 a = *(const bf16_8*)(aptr + k);
        bf16_8 br = *(const bf16_8*)(bpr + k);
        bf16_8 bz = *(const bf16_8*)(bpz + k);
        bf16_8 bn = *(const bf16_8*)(bpn + k);
        accr = __builtin_amdgcn_mfma_f32_16x16x32_bf16(a, br, accr, 0, 0, 0);
        accz = __builtin_amdgcn_mfma_f32_16x16x32_bf16(a, bz, accz, 0, 0, 0);
        accn = __builtin_amdgcn_mfma_f32_16x16x32_bf16(a, bn, accn, 0, 0, 0);
    }

    const int er = lane >> 4;
    const int ec = lane & 15;
#pragma unroll
    for (int i = 0; i < 4; i++) {
        int b = mt * 16 + er * 4 + i;
        int j = j0 + ec;
        float ghr = accr[i] + b_hh[j];
        float ghz = accz[i] + b_hh[HID + j];
        float ghn = accn[i] + b_hh[2 * HID + j];
        float gir = gi_s[b * 3 * HID + j];
        float giz = gi_s[b * 3 * HID + HID + j];
        float gin = gi_s[b * 3 * HID + 2 * HID + j];
        float r = 1.f / (1.f + __expf(-(gir + ghr)));
        float z = 1.f / (1.f + __expf(-(giz + ghz)));
        float n = tanhf(gin + r * ghn);
        float ho = hf_s[b * HID + j];
        float hn = (1.f - z) * n + z * ho;
        hf_out[b * HID + j] = hn;
        hb_out[b * HID + j] = f32_to_bf16_rne(hn);
    }
}

extern "C" void kernel_launch(void* const* d_in, const int* in_sizes, int n_in,
                              void* d_out, int out_size, void* d_ws, size_t ws_size,
                              hipStream_t stream) {
    const int* x = (const int*)d_in[0];
    const float* hidden = (const float*)d_in[1];
    const float* emb = (const float*)d_in[2];
    const float* w_ih = (const float*)d_in[3];
    const float* w_hh = (const float*)d_in[4];
    const float* b_ih = (const float*)d_in[5];
    const float* b_hh = (const float*)d_in[6];
    const float* w_out = (const float*)d_in[7];
    const float* b_out = (const float*)d_in[8];
    float* out = (float*)d_out;

    char* ws = (char*)d_ws;
    // workspace layout (all offsets 256B aligned)
    unsigned short* w_ih_bf  = (unsigned short*)(ws + 0);            //  3,145,728 B
    unsigned short* w_hh_bf  = (unsigned short*)(ws + 3145728);      //  6,291,456 B
    unsigned short* w_out_bf = (unsigned short*)(ws + 9437184);      // 65,536,000 B
    unsigned short* e_bf     = (unsigned short*)(ws + 74973184);     //  4,194,304 B
    float*          gi       = (float*)(ws + 79167488);              // 50,331,648 B
    float*          hf       = (float*)(ws + 129499136);             // 17,039,360 B (65 steps)
    unsigned short* hb       = (unsigned short*)(ws + 146538496);    //  8,519,680 B
    // total 155,058,176 B

    // 1. convert weights to bf16
    f32_to_bf16_vec<<<(3 * HID * EMB / 4 + 255) / 256, 256, 0, stream>>>(w_ih, w_ih_bf, 3 * HID * EMB / 4);
    f32_to_bf16_vec<<<(3 * HID * HID / 4 + 255) / 256, 256, 0, stream>>>(w_hh, w_hh_bf, 3 * HID * HID / 4);
    f32_to_bf16_vec<<<(VOCAB * HID / 4 + 255) / 256, 256, 0, stream>>>(w_out, w_out_bf, VOCAB * HID / 4);

    // 2. h0 -> hf[0], hb[0]
    init_h_kernel<<<BATCH * HID / 256, 256, 0, stream>>>(hidden, hf, hb);

    // 3. embedding gather + relu -> e_bf (4096, 512)
    embed_relu_kernel<<<SEQ * BATCH * EMB / 256, 256, 0, stream>>>(x, emb, e_bf);

    // 4. gi = e @ w_ih^T + b_ih : (4096, 3072), K=512
    {
        dim3 grid(3 * HID / 128, SEQ * BATCH / 128);
        gemm_bf16_nt<<<grid, 256, 0, stream>>>(e_bf, w_ih_bf, b_ih, gi,
                                               SEQ * BATCH, 3 * HID, EMB, 0);
    }

    // 5. 64 sequential GRU steps
    for (int s = 0; s < SEQ; s++) {
        gru_step_kernel<<<256, 64, 0, stream>>>(
            hb + (long)s * BATCH * HID,
            hf + (long)s * BATCH * HID,
            w_hh_bf,
            gi + (long)s * BATCH * 3 * HID,
            b_hh,
            hb + (long)(s + 1) * BATCH * HID,
            hf + (long)(s + 1) * BATCH * HID);
    }

    // 6. logits = hs @ w_out^T + b_out, stored as (B, S, V)
    {
        dim3 grid(VOCAB / 128, SEQ * BATCH / 128);
        gemm_bf16_nt<<<grid, 256, 0, stream>>>(hb + BATCH * HID, w_out_bf, b_out, out,
                                               SEQ * BATCH, VOCAB, HID, 1);
    }
}